// Round 14
// baseline (264.216 us; speedup 1.0000x reference)
//
#include <hip/hip_runtime.h>
#include <stdint.h>
#include <math.h>

typedef unsigned short u16;
typedef short bf16x8 __attribute__((ext_vector_type(8)));
typedef unsigned short u16x8 __attribute__((ext_vector_type(8)));
typedef unsigned short u16x4 __attribute__((ext_vector_type(4)));
typedef float f32x4 __attribute__((ext_vector_type(4)));

typedef __attribute__((address_space(1))) const void gvoid;
typedef __attribute__((address_space(3))) void lvoid;

#define LOG2E 1.4426950408889634f

__device__ __forceinline__ float bf2f(u16 u) {
  union { unsigned int i; float f; } v; v.i = ((unsigned int)u) << 16; return v.f;
}
__device__ __forceinline__ u16 f2bf(float f) {
  union { float ff; unsigned int i; } v; v.ff = f;
  unsigned int x = v.i;
  return (u16)((x + 0x7FFFu + ((x >> 16) & 1u)) >> 16);
}

// T1 bijective chunked XCD swizzle (nwg % 8 == 0): consecutive remapped
// wgid (which share operand panels) land on the SAME XCD's L2.
__device__ __forceinline__ int xcd_swz(int o, int nwg) {
  return (o & 7) * (nwg >> 3) + (o >> 3);
}

// ---------------------------------------------------------------------------
// fp32 -> bf16 flat convert of TWO buffers in one dispatch (Q then K).
// ---------------------------------------------------------------------------
__global__ __launch_bounds__(256)
void cvt2_f32_bf16(const float* __restrict__ s0, u16* __restrict__ d0,
                   const float* __restrict__ s1, u16* __restrict__ d1, long n)
{
  const long nb = n / 2048;
  const float* src = (blockIdx.x < nb) ? s0 : s1;
  u16* dst         = (blockIdx.x < nb) ? d0 : d1;
  const long bid   = (blockIdx.x < nb) ? blockIdx.x : (blockIdx.x - nb);
  long i = (bid * 256 + threadIdx.x) * 8;
  if (i + 8 > n) return;
  f32x4 a = *(const f32x4*)&src[i];
  f32x4 b = *(const f32x4*)&src[i + 4];
  u16x8 o;
#pragma unroll
  for (int j = 0; j < 4; j++) { o[j] = f2bf(a[j]); o[4 + j] = f2bf(b[j]); }
  *(u16x8*)&dst[i] = o;
}

__global__ __launch_bounds__(256)
void cvt_f32_bf16(const float* __restrict__ src, u16* __restrict__ dst, long n)
{
  long i = ((long)blockIdx.x * 256 + threadIdx.x) * 8;
  if (i + 8 > n) return;
  f32x4 a = *(const f32x4*)&src[i];
  f32x4 b = *(const f32x4*)&src[i + 4];
  u16x8 o;
#pragma unroll
  for (int j = 0; j < 4; j++) { o[j] = f2bf(a[j]); o[4 + j] = f2bf(b[j]); }
  *(u16x8*)&dst[i] = o;
}

// ---------------------------------------------------------------------------
// Per-batch transpose+convert: VT[b][n][k] = (bf16)V[b][k][n]. 64x64 tiles.
// ---------------------------------------------------------------------------
__global__ __launch_bounds__(256)
void transcvt_v(const float* __restrict__ V, u16* __restrict__ VT, int S, int E)
{
  __shared__ u16 t[64][72];
  const int b = blockIdx.z;
  const float* Vb = V + (long)b * S * E;
  u16* VTb = VT + (long)b * S * E;
  const int k0 = blockIdx.x * 64, n0 = blockIdx.y * 64;
  const int tid = threadIdx.x;
#pragma unroll
  for (int p = 0; p < 2; p++) {
    int kk = p * 32 + (tid >> 3);
    int nn = (tid & 7) * 8;
    f32x4 a = *(const f32x4*)&Vb[(long)(k0 + kk) * E + n0 + nn];
    f32x4 c = *(const f32x4*)&Vb[(long)(k0 + kk) * E + n0 + nn + 4];
#pragma unroll
    for (int j = 0; j < 4; j++) { t[nn + j][kk] = f2bf(a[j]); t[nn + 4 + j][kk] = f2bf(c[j]); }
  }
  __syncthreads();
#pragma unroll
  for (int p = 0; p < 2; p++) {
    int nn = p * 32 + (tid >> 3);
    int kk = (tid & 7) * 8;
    u16x8 u;
#pragma unroll
    for (int j = 0; j < 8; j++) u[j] = t[nn][kk + j];
    *(u16x8*)&VTb[(long)(n0 + nn) * S + k0 + kk] = u;
  }
}

// ===========================================================================
// 256x256 / 8-phase / counted-vmcnt bf16 GEMM (B^T layout), T3+T4+T5 + T2
// + T1 XCD swizzle (1D grid). (Schedule verified rounds 9/10.)
// ===========================================================================
__global__ __launch_bounds__(512, 1)
void gemm_bt_256(const u16* __restrict__ A, int lda,
                 const u16* __restrict__ B, int ldb, long bBatchStride,
                 u16* __restrict__ C, int ldc,
                 int K, float scale, int S, int nbx)
{
  __shared__ u16 LA[2][256][64];
  __shared__ u16 LB[2][256][64];

  const int tid  = threadIdx.x;
  const int lane = tid & 63;
  const int wave = tid >> 6;        // 0..7
  const int wm   = wave >> 2;       // 0..1
  const int wn   = wave & 3;        // 0..3

  const int wgid = xcd_swz(blockIdx.x, gridDim.x);
  const int by   = wgid / nbx;
  const int bx   = wgid - by * nbx;

  const long gTile = (long)by * 256;
  const int  bidx  = (int)(gTile / S);
  const int  nTile = bx * 256;

  const u16* Ab = A + gTile * (long)lda;
  const u16* Bb = B + (long)bidx * bBatchStride + (long)nTile * ldb;

  const int lm  = lane & 15;
  const int lmx = lm & 7;
  const int l47 = lane >> 4;
  const int srw = lane >> 3;
  const int scg = (((lane & 7) ^ (lane >> 3)) * 8);   // T2 pre-swizzled src granule

  f32x4 acc[8][4];
#pragma unroll
  for (int i = 0; i < 8; i++)
#pragma unroll
    for (int j = 0; j < 4; j++) acc[i][j] = (f32x4){0.f, 0.f, 0.f, 0.f};

  bf16x8 afr[8], bA[4], bB[4];

#define STG_A(buf, T, h)                                                      \
  {                                                                           \
    _Pragma("unroll")                                                         \
    for (int p_ = 0; p_ < 2; p_++) {                                          \
      const int ch_ = wave * 2 + p_;                                          \
      const int rr_ = (h) * 128 + ch_ * 8 + srw;                              \
      __builtin_amdgcn_global_load_lds(                                       \
          (gvoid*)&Ab[(long)rr_ * lda + (T) * 64 + scg],                      \
          (lvoid*)((char*)&LA[0][0][0] + (buf) * 32768 + (h) * 16384 + ch_ * 1024), \
          16, 0, 0);                                                          \
    }                                                                         \
  }
#define STG_B(buf, T, h)                                                      \
  {                                                                           \
    _Pragma("unroll")                                                         \
    for (int p_ = 0; p_ < 2; p_++) {                                          \
      const int ch_ = wave * 2 + p_;                                          \
      const int rr_ = (h) * 128 + ch_ * 8 + srw;                              \
      __builtin_amdgcn_global_load_lds(                                       \
          (gvoid*)&Bb[(long)rr_ * ldb + (T) * 64 + scg],                      \
          (lvoid*)((char*)&LB[0][0][0] + (buf) * 32768 + (h) * 16384 + ch_ * 1024), \
          16, 0, 0);                                                          \
    }                                                                         \
  }
#define LDA_HALF(buf, mh)                                                     \
  {                                                                           \
    _Pragma("unroll")                                                         \
    for (int m_ = 0; m_ < 4; m_++)                                            \
      _Pragma("unroll")                                                       \
      for (int kk_ = 0; kk_ < 2; kk_++)                                       \
        afr[m_ * 2 + kk_] = *(const bf16x8*)&LA[buf][wm * 128 + ((mh) * 4 + m_) * 16 + lm][(((kk_ * 4 + l47) ^ lmx) * 8)]; \
  }
#define LDB_HALF(buf, nh, dst)                                                \
  {                                                                           \
    _Pragma("unroll")                                                         \
    for (int n_ = 0; n_ < 2; n_++)                                            \
      _Pragma("unroll")                                                       \
      for (int kk_ = 0; kk_ < 2; kk_++)                                       \
        dst[n_ * 2 + kk_] = *(const bf16x8*)&LB[buf][wn * 64 + ((nh) * 2 + n_) * 16 + lm][(((kk_ * 4 + l47) ^ lmx) * 8)]; \
  }
#define PH(mh, nh, bp)                                                        \
  {                                                                           \
    __builtin_amdgcn_sched_barrier(0);                                        \
    __builtin_amdgcn_s_barrier();                                             \
    asm volatile("s_waitcnt lgkmcnt(0)" ::: "memory");                        \
    __builtin_amdgcn_sched_barrier(0);                                        \
    __builtin_amdgcn_s_setprio(1);                                            \
    _Pragma("unroll")                                                         \
    for (int m_ = 0; m_ < 4; m_++)                                            \
      _Pragma("unroll")                                                       \
      for (int n_ = 0; n_ < 2; n_++)                                          \
        _Pragma("unroll")                                                     \
        for (int kk_ = 0; kk_ < 2; kk_++)                                     \
          acc[(mh) * 4 + m_][(nh) * 2 + n_] =                                 \
              __builtin_amdgcn_mfma_f32_16x16x32_bf16(                        \
                  afr[m_ * 2 + kk_], bp[n_ * 2 + kk_],                        \
                  acc[(mh) * 4 + m_][(nh) * 2 + n_], 0, 0, 0);                \
    __builtin_amdgcn_s_setprio(0);                                            \
    __builtin_amdgcn_sched_barrier(0);                                        \
    __builtin_amdgcn_s_barrier();                                             \
  }

  const int NT = K >> 6;
  const int NI = NT >> 1;

  STG_A(0, 0, 0); STG_A(0, 0, 1); STG_B(0, 0, 0); STG_B(0, 0, 1);
  STG_A(1, 1, 0); STG_B(1, 1, 0);
  asm volatile("s_waitcnt vmcnt(0)" ::: "memory");
  __builtin_amdgcn_sched_barrier(0);
  __builtin_amdgcn_s_barrier();

  for (int i = 0; i < NI - 1; i++) {
    const int t0 = 2 * i, t1 = t0 + 1;
    LDA_HALF(0, 0); LDB_HALF(0, 0, bA);
    STG_B(1, t1, 1);
    PH(0, 0, bA);
    LDB_HALF(0, 1, bB);
    STG_A(1, t1, 1);
    PH(0, 1, bB);
    LDA_HALF(0, 1);
    STG_A(0, t0 + 2, 0);
    PH(1, 0, bA);
    STG_B(0, t0 + 2, 0);
    asm volatile("s_waitcnt vmcnt(4)" ::: "memory");
    PH(1, 1, bB);
    LDA_HALF(1, 0); LDB_HALF(1, 0, bA);
    STG_B(0, t0 + 2, 1);
    PH(0, 0, bA);
    LDB_HALF(1, 1, bB);
    STG_A(0, t0 + 2, 1);
    PH(0, 1, bB);
    LDA_HALF(1, 1);
    STG_A(1, t1 + 2, 0);
    PH(1, 0, bA);
    STG_B(1, t1 + 2, 0);
    asm volatile("s_waitcnt vmcnt(4)" ::: "memory");
    PH(1, 1, bB);
  }

  {
    const int t1 = NT - 1;
    LDA_HALF(0, 0); LDB_HALF(0, 0, bA);
    STG_B(1, t1, 1);
    PH(0, 0, bA);
    LDB_HALF(0, 1, bB);
    STG_A(1, t1, 1);
    PH(0, 1, bB);
    LDA_HALF(0, 1);
    PH(1, 0, bA);
    asm volatile("s_waitcnt vmcnt(0)" ::: "memory");
    PH(1, 1, bB);
    LDA_HALF(1, 0); LDB_HALF(1, 0, bA);
    PH(0, 0, bA);
    LDB_HALF(1, 1, bB);
    PH(0, 1, bB);
    LDA_HALF(1, 1);
    PH(1, 0, bA);
    PH(1, 1, bB);
  }

  const int lr = (lane >> 4) * 4;
#pragma unroll
  for (int mf = 0; mf < 8; mf++) {
#pragma unroll
    for (int nf = 0; nf < 4; nf++) {
      long gr = gTile + wm * 128 + mf * 16 + lr;
      int  cc = nTile + wn * 64 + nf * 16 + lm;
#pragma unroll
      for (int i2 = 0; i2 < 4; i2++)
        C[(gr + i2) * (long)ldc + cc] = f2bf(acc[mf][nf][i2] * scale);
    }
  }
#undef STG_A
#undef STG_B
#undef LDA_HALF
#undef LDB_HALF
#undef PH
}

// ===========================================================================
// PV GEMM v3: 1 phase per K-tile (32 MFMA/phase), 3-buffer LDS ring.
// BM=256 x BN=128, 8 waves 4Mx2N, per-wave 64x64, acc[4][4]. BK=64.
// Ring invariants (mirroring the verified R12 discipline):
//  - P(t) reads buf[t%3]; tile t was CONFIRMED at P(t-1)'s vmcnt(6) and
//    published by P(t-1)'s barriers (confirm-before-read).
//  - P(t) stages tile t+2 into buf[(t+2)%3] == buf[(t-1)%3], the slot whose
//    reads finished before P(t-1)'s closing barrier (stage-into-freed-slot).
//  - vmcnt(6) at P(t): outstanding = t+1(6) + t+2(6) -> drains t+1, keeps 6
//    in flight (never drain to 0 mid-loop).
// Tail (requires (NT-2)%3==0, NT>=5): P(NT-2) vmcnt(0), P(NT-1) no wait.
// LDS = LA[3][256][64] + LB[3][128][64] = 144 KB. fp32 out. T1+T2 kept.
// ===========================================================================
__global__ __launch_bounds__(512, 1)
void gemm_pv_256(const u16* __restrict__ A, int lda,
                 const u16* __restrict__ B, int ldb, long bBatchStride,
                 float* __restrict__ C, int ldc,
                 int K, int S, int nbx)
{
  __shared__ u16 LA[3][256][64];   // 96 KB
  __shared__ u16 LB[3][128][64];   // 48 KB

  const int tid  = threadIdx.x;
  const int lane = tid & 63;
  const int wave = tid >> 6;        // 0..7
  const int wm   = wave >> 1;       // 0..3  (M quarter, 64 rows)
  const int wn   = wave & 1;        // 0..1  (N half, 64 cols)

  const int wgid = xcd_swz(blockIdx.x, gridDim.x);
  const int by   = wgid / nbx;
  const int bx   = wgid - by * nbx;

  const long gTile = (long)by * 256;
  const int  bidx  = (int)(gTile / S);
  const int  nTile = bx * 128;

  const u16* Ab = A + gTile * (long)lda;
  const u16* Bb = B + (long)bidx * bBatchStride + (long)nTile * ldb;

  const int lm  = lane & 15;
  const int lmx = lm & 7;
  const int l47 = lane >> 4;
  const int srw = lane >> 3;
  const int scg = (((lane & 7) ^ (lane >> 3)) * 8);   // T2 pre-swizzled src granule

  f32x4 acc[4][4];
#pragma unroll
  for (int i = 0; i < 4; i++)
#pragma unroll
    for (int j = 0; j < 4; j++) acc[i][j] = (f32x4){0.f, 0.f, 0.f, 0.f};

  bf16x8 afr[8], ball[8];

// stage one full K-tile T into ring slot buf: A 4 loads + B 2 loads = 6.
#define STG_T(buf, T)                                                         \
  {                                                                           \
    _Pragma("unroll")                                                         \
    for (int h_ = 0; h_ < 2; h_++) {                                          \
      _Pragma("unroll")                                                       \
      for (int p_ = 0; p_ < 2; p_++) {                                        \
        const int ch_ = wave * 2 + p_;                                        \
        const int rr_ = h_ * 128 + ch_ * 8 + srw;                             \
        __builtin_amdgcn_global_load_lds(                                     \
            (gvoid*)&Ab[(long)rr_ * lda + (T) * 64 + scg],                    \
            (lvoid*)((char*)&LA[0][0][0] + (buf) * 32768 + h_ * 16384 + ch_ * 1024), \
            16, 0, 0);                                                        \
      }                                                                       \
      const int rb_ = h_ * 64 + wave * 8 + srw;                               \
      __builtin_amdgcn_global_load_lds(                                       \
          (gvoid*)&Bb[(long)rb_ * ldb + (T) * 64 + scg],                      \
          (lvoid*)((char*)&LB[0][0][0] + (buf) * 16384 + h_ * 8192 + wave * 1024), \
          16, 0, 0);                                                          \
    }                                                                         \
  }
// all fragments for one K-tile: A 8 reads, B 8 reads.
#define LD_ALL(buf)                                                           \
  {                                                                           \
    _Pragma("unroll")                                                         \
    for (int m_ = 0; m_ < 4; m_++)                                            \
      _Pragma("unroll")                                                       \
      for (int kk_ = 0; kk_ < 2; kk_++)                                       \
        afr[m_ * 2 + kk_] = *(const bf16x8*)&LA[buf][wm * 64 + m_ * 16 + lm][(((kk_ * 4 + l47) ^ lmx) * 8)]; \
    _Pragma("unroll")                                                         \
    for (int n_ = 0; n_ < 4; n_++)                                            \
      _Pragma("unroll")                                                       \
      for (int kk_ = 0; kk_ < 2; kk_++)                                       \
        ball[n_ * 2 + kk_] = *(const bf16x8*)&LB[buf][wn * 64 + n_ * 16 + lm][(((kk_ * 4 + l47) ^ lmx) * 8)]; \
  }
// one phase's sync + 32-MFMA tile
#define PH32()                                                                \
  {                                                                           \
    __builtin_amdgcn_sched_barrier(0);                                        \
    __builtin_amdgcn_s_barrier();                                             \
    asm volatile("s_waitcnt lgkmcnt(0)" ::: "memory");                        \
    __builtin_amdgcn_sched_barrier(0);                                        \
    __builtin_amdgcn_s_setprio(1);                                            \
    _Pragma("unroll")                                                         \
    for (int m_ = 0; m_ < 4; m_++)                                            \
      _Pragma("unroll")                                                       \
      for (int n_ = 0; n_ < 4; n_++)                                          \
        _Pragma("unroll")                                                     \
        for (int kk_ = 0; kk_ < 2; kk_++)                                     \
          acc[m_][n_] = __builtin_amdgcn_mfma_f32_16x16x32_bf16(              \
              afr[m_ * 2 + kk_], ball[n_ * 2 + kk_], acc[m_][n_], 0, 0, 0);   \
    __builtin_amdgcn_s_setprio(0);                                            \
    __builtin_amdgcn_sched_barrier(0);                                        \
    __builtin_amdgcn_s_barrier();                                             \
  }

  const int NT = K >> 6;              // gated: NT >= 5, (NT-2) % 3 == 0

  // prologue: stage t0, t1; confirm t0 (drain 6 oldest, keep t1 in flight)
  STG_T(0, 0); STG_T(1, 1);
  asm volatile("s_waitcnt vmcnt(6)" ::: "memory");
  __builtin_amdgcn_sched_barrier(0);
  __builtin_amdgcn_s_barrier();

  int t = 0;
  for (; t + 4 < NT; t += 3) {
    // P(t): buf0; stage t+2 -> buf2 (freed at P(t-1)); confirm t+1
    LD_ALL(0);
    STG_T(2, t + 2);
    asm volatile("s_waitcnt vmcnt(6)" ::: "memory");
    PH32();
    // P(t+1): buf1; stage t+3 -> buf0; confirm t+2
    LD_ALL(1);
    STG_T(0, t + 3);
    asm volatile("s_waitcnt vmcnt(6)" ::: "memory");
    PH32();
    // P(t+2): buf2; stage t+4 -> buf1; confirm t+3
    LD_ALL(2);
    STG_T(1, t + 4);
    asm volatile("s_waitcnt vmcnt(6)" ::: "memory");
    PH32();
  }
  // tail: t == NT-2 (buf0), NT-1 (buf1); nothing left to stage.
  LD_ALL(0);
  asm volatile("s_waitcnt vmcnt(0)" ::: "memory");   // confirm NT-1
  PH32();
  LD_ALL(1);
  PH32();

  // epilogue: fp32 out; C/D layout col = lane&15, row = (lane>>4)*4 + reg
  const int lr = (lane >> 4) * 4;
#pragma unroll
  for (int mf = 0; mf < 4; mf++) {
#pragma unroll
    for (int nf = 0; nf < 4; nf++) {
      long gr = gTile + wm * 64 + mf * 16 + lr;
      int  cc = nTile + wn * 64 + nf * 16 + lm;
#pragma unroll
      for (int i2 = 0; i2 < 4; i2++)
        C[(gr + i2) * (long)ldc + cc] = acc[mf][nf][i2];
    }
  }
#undef STG_T
#undef LD_ALL
#undef PH32
}

// ---------------------------------------------------------------------------
// FAST bf16 GEMM (BT layout), m97 structure (fallback chunked path).
// ---------------------------------------------------------------------------
template<int HASMASK, int COUT>
__global__ __launch_bounds__(256, 3)
void gemm_bt_fast(const u16* __restrict__ A, int lda, long aRowOff,
                  const u16* __restrict__ B, int ldb, long bBatchStride,
                  void* __restrict__ Cp, int ldc, long cRowOff,
                  const float* __restrict__ maskf,
                  int K, float scale, long g0, int S)
{
  const int tid  = threadIdx.x;
  const int lane = tid & 63;
  const int wave = tid >> 6;
  const long gTile = g0 + (long)blockIdx.y * 128;
  const int  bidx  = (int)(gTile / S);
  const int  nTile = blockIdx.x * 128;

  __shared__ u16 As[128][32];
  __shared__ u16 Bs[128][32];

  const u16* Ab = A + (gTile - aRowOff) * (long)lda;
  const u16* Bb = B + (long)bidx * bBatchStride + (long)nTile * ldb;

  const int qm = (wave >> 1) * 64;
  const int qn = (wave & 1) * 64;
  const int lm  = lane & 15;
  const int lkB = (lane >> 4) * 16;

  const int sr = lane >> 2;
  const int sc = (lane & 3) * 8;

  f32x4 acc[4][4];
#pragma unroll
  for (int i = 0; i < 4; i++)
#pragma unroll
    for (int j = 0; j < 4; j++) acc[i][j] = (f32x4){0.f, 0.f, 0.f, 0.f};

  for (int k0 = 0; k0 < K; k0 += 32) {
#pragma unroll
    for (int p = 0; p < 2; p++) {
      const int chunk = wave * 2 + p;
      const int r = chunk * 16 + sr;
      __builtin_amdgcn_global_load_lds(
          (gvoid*)&Ab[(long)r * lda + k0 + sc],
          (lvoid*)((char*)&As[0][0] + chunk * 1024),
          16, 0, 0);
      __builtin_amdgcn_global_load_lds(
          (gvoid*)&Bb[(long)r * ldb + k0 + sc],
          (lvoid*)((char*)&Bs[0][0] + chunk * 1024),
          16, 0, 0);
    }
    __syncthreads();

    bf16x8 af[4], bfr[4];
#pragma unroll
    for (int rt = 0; rt < 4; rt++)
      af[rt] = *(const bf16x8*)((const char*)&As[qm + rt * 16 + lm][0] + lkB);
#pragma unroll
    for (int ct = 0; ct < 4; ct++)
      bfr[ct] = *(const bf16x8*)((const char*)&Bs[qn + ct * 16 + lm][0] + lkB);

#pragma unroll
    for (int rt = 0; rt < 4; rt++)
#pragma unroll
      for (int ct = 0; ct < 4; ct++)
        acc[rt][ct] = __builtin_amdgcn_mfma_f32_16x16x32_bf16(af[rt], bfr[ct], acc[rt][ct], 0, 0, 0);
    __syncthreads();
  }

  const int lr = (lane >> 4) * 4;
#pragma unroll
  for (int rt = 0; rt < 4; rt++) {
#pragma unroll
    for (int ct = 0; ct < 4; ct++) {
      long gr = gTile + qm + rt * 16 + lr;
      int  cc = nTile + qn + ct * 16 + lm;
#pragma unroll
      for (int i = 0; i < 4; i++) {
        float v = acc[rt][ct][i] * scale;
        if (HASMASK) v += maskf[(gr + i) * (long)ldc + cc];
        if (COUT == 0)
          ((u16*)Cp)[(gr + i - cRowOff) * (long)ldc + cc] = f2bf(v);
        else
          ((float*)Cp)[(gr + i - cRowOff) * (long)ldc + cc] = v;
      }
    }
  }
}

// ---------------------------------------------------------------------------
// GEMM (BT layout) — generic fallback (fp32 sources, no-workspace path).
// ---------------------------------------------------------------------------
template<int ASRC, int BSRC, int BMODE, int HASMASK, int COUT>
__global__ __launch_bounds__(256, 2)
void gemm_bt(const void* __restrict__ Ap, int lda, long aRowOff,
             const void* __restrict__ Bp, int ldb, long bBatchStride,
             void* __restrict__ Cp, int ldc, long cRowOff,
             const float* __restrict__ maskf,
             int K, float scale, long g0, int S)
{
  const int tid  = threadIdx.x;
  const int lane = tid & 63;
  const int wave = tid >> 6;
  const long gTile = g0 + (long)blockIdx.y * 128;
  const int  b     = (int)(gTile / S);
  const int  nTile = blockIdx.x * 128;

  __shared__ u16 As[128][40];
  __shared__ u16 Bs[128][40];

  const int qm = (wave >> 1) * 64;
  const int qn = (wave & 1) * 64;

  f32x4 acc[4][4];
#pragma unroll
  for (int i = 0; i < 4; i++)
#pragma unroll
    for (int j = 0; j < 4; j++) acc[i][j] = (f32x4){0.f, 0.f, 0.f, 0.f};

  const u16*   Ab = (const u16*)Ap   + (gTile - aRowOff) * (long)lda;
  const float* Af = (const float*)Ap + (gTile - aRowOff) * (long)lda;
  const u16*   Bb = (const u16*)Bp   + (long)b * bBatchStride;
  const float* Bf = (const float*)Bp + (long)b * bBatchStride;

  const int lm = lane & 15;
  const int lk = (lane >> 4) * 8;

  for (int k0 = 0; k0 < K; k0 += 32) {
    if (ASRC == 0) {
      int srow = tid >> 2, scol = (tid & 3) * 8;
#pragma unroll
      for (int p = 0; p < 2; p++) {
        int r = p * 64 + srow;
        *(u16x8*)&As[r][scol] = *(const u16x8*)&Ab[(long)r * lda + k0 + scol];
      }
    } else {
      int srow = tid >> 3, scol = (tid & 7) * 4;
#pragma unroll
      for (int p = 0; p < 4; p++) {
        int r = p * 32 + srow;
        f32x4 a = *(const f32x4*)&Af[(long)r * lda + k0 + scol];
        u16x4 o;
#pragma unroll
        for (int j = 0; j < 4; j++) o[j] = f2bf(a[j]);
        *(u16x4*)&As[r][scol] = o;
      }
    }
    if (BMODE == 0) {
      if (BSRC == 0) {
        int srow = tid >> 2, scol = (tid & 3) * 8;
#pragma unroll
        for (int p = 0; p < 2; p++) {
          int r = p * 64 + srow;
          *(u16x8*)&Bs[r][scol] = *(const u16x8*)&Bb[(long)(nTile + r) * ldb + k0 + scol];
        }
      } else {
        int srow = tid >> 3, scol = (tid & 7) * 4;
#pragma unroll
        for (int p = 0; p < 4; p++) {
          int r = p * 32 + srow;
          f32x4 a = *(const f32x4*)&Bf[(long)(nTile + r) * ldb + k0 + scol];
          u16x4 o;
#pragma unroll
          for (int j = 0; j < 4; j++) o[j] = f2bf(a[j]);
          *(u16x4*)&Bs[r][scol] = o;
        }
      }
    }
    __syncthreads();

    bf16x8 af[4], bfr[4];
#pragma unroll
    for (int rt = 0; rt < 4; rt++)
      af[rt] = *(const bf16x8*)&As[qm + rt * 16 + lm][lk];
    if (BMODE == 0) {
#pragma unroll
      for (int ct = 0; ct < 4; ct++)
        bfr[ct] = *(const bf16x8*)&Bs[qn + ct * 16 + lm][lk];
    } else {
#pragma unroll
      for (int ct = 0; ct < 4; ct++) {
        const float* vp = Bf + (long)(k0 + lk) * ldb + nTile + qn + ct * 16 + lm;
#pragma unroll
        for (int j = 0; j < 8; j++) bfr[ct][j] = (short)f2bf(vp[(long)j * ldb]);
      }
    }
#pragma unroll
    for (int rt = 0; rt < 4; rt++)
#pragma unroll
      for (int ct = 0; ct < 4; ct++)
        acc[rt][ct] = __builtin_amdgcn_mfma_f32_16x16x32_bf16(af[rt], bfr[ct], acc[rt][ct], 0, 0, 0);
    __syncthreads();
  }

  const int lr = (lane >> 4) * 4;
#pragma unroll
  for (int rt = 0; rt < 4; rt++) {
#pragma unroll
    for (int ct = 0; ct < 4; ct++) {
      long gr = gTile + qm + rt * 16 + lr;
      int  cc = nTile + qn + ct * 16 + lm;
#pragma unroll
      for (int i = 0; i < 4; i++) {
        float v = acc[rt][ct][i] * scale;
        if (HASMASK) v += maskf[(gr + i) * (long)ldc + cc];
        if (COUT == 0)
          ((u16*)Cp)[(gr + i - cRowOff) * (long)ldc + cc] = f2bf(v);
        else
          ((float*)Cp)[(gr + i - cRowOff) * (long)ldc + cc] = v;
      }
    }
  }
}

// ---------------------------------------------------------------------------
// Wave-per-row softmax (+fp32 mask add), 4 rows per 256-thr block.
// ---------------------------------------------------------------------------
__global__ __launch_bounds__(256)
void softmax_rows_wave(u16* __restrict__ Sbuf, const float* __restrict__ maskf,
                       int ncols)
{
  const int wave = threadIdx.x >> 6;
  const int lane = threadIdx.x & 63;
  const long row = (long)blockIdx.x * 4 + wave;
  u16* rp = Sbuf + row * (long)ncols;
  const float* mp = maskf + row * (long)ncols;

  float x[32];
  float m = -3.0e38f;
#pragma unroll
  for (int j = 0; j < 4; j++) {
    const int c = j * 512 + lane * 8;
    u16x8 u = *(const u16x8*)&rp[c];
    f32x4 ma = *(const f32x4*)&mp[c];
    f32x4 mb = *(const f32x4*)&mp[c + 4];
#pragma unroll
    for (int i = 0; i < 4; i++) {
      x[j * 8 + i]     = bf2f(u[i])     + ma[i];
      x[j * 8 + 4 + i] = bf2f(u[4 + i]) + mb[i];
    }
#pragma unroll
    for (int i = 0; i < 8; i++) m = fmaxf(m, x[j * 8 + i]);
  }
#pragma unroll
  for (int off = 32; off; off >>= 1) m = fmaxf(m, __shfl_xor(m, off, 64));

  float s = 0.f;
#pragma unroll
  for (int i = 0; i < 32; i++) { x[i] = exp2f((x[i] - m) * LOG2E); s += x[i]; }
#pragma unroll
  for (int off = 32; off; off >>= 1) s += __shfl_xor(s, off, 64);
  const float inv = 1.0f / s;

#pragma unroll
  for (int j = 0; j < 4; j++) {
    const int c = j * 512 + lane * 8;
    u16x8 o;
#pragma unroll
    for (int i = 0; i < 8; i++) o[i] = f2bf(x[j * 8 + i] * inv);
    *(u16x8*)&rp[c] = o;
  }
}

// ---------------------------------------------------------------------------
// Row softmax in place (fallback path), bf16 rows of length ncols == 2048.
// ---------------------------------------------------------------------------
template<int HASM>
__global__ __launch_bounds__(256)
void softmax_rows(u16* __restrict__ Sbuf, const float* __restrict__ maskf, int ncols)
{
  const long row = blockIdx.x;
  u16* rp = Sbuf + row * (long)ncols;
  const int tid = threadIdx.x;

  u16x8 u = *(const u16x8*)&rp[tid * 8];
  float x[8];
  if (HASM) {
    const float* mp = maskf + row * (long)ncols + tid * 8;
    f32x4 ma = *(const f32x4*)&mp[0];
    f32x4 mb = *(const f32x4*)&mp[4];
#pragma unroll
    for (int i = 0; i < 4; i++) { x[i] = bf2f(u[i]) + ma[i]; x[4 + i] = bf2f(u[4 + i]) + mb[i]; }
  } else {
#pragma unroll
    for (int i = 0; i < 8; i++) x[i] = bf2f(u[i]);
  }
  float m = -3.0e38f;
#pragma unroll
  for (int i = 0; i < 8; i++) m = fmaxf(m, x[i]);
#pragma unroll
  for (int off = 32; off; off >>= 1) m = fmaxf(m, __shfl_xor(m, off, 64));
  __shared__ float redm[4];
  if ((tid & 63) == 0) redm[tid >> 6] = m;
  __syncthreads();
  m = fmaxf(fmaxf(redm[0], redm[1]), fmaxf(redm[2], redm[3]));

  float e[8];
  float s = 0.f;
#pragma unroll
  for (int i = 0; i < 8; i++) { e[i] = exp2f((x[i] - m) * LOG2E); s += e[i]; }
#pragma unroll
  for (int off = 32; off; off >>= 1) s += __shfl_xor(s, off, 64);
  __shared__ float reds[4];
  if ((tid & 63) == 0) reds[tid >> 6] = s;
  __syncthreads();
  s = reds[0] + reds[1] + reds[2] + reds[3];

  float inv = 1.0f / s;
  u16x8 o;
#pragma unroll
  for (int i = 0; i < 8; i++) o[i] = f2bf(e[i] * inv);
  *(u16x8*)&rp[tid * 8] = o;
}

extern "C" void kernel_launch(void* const* d_in, const int* in_sizes, int n_in,
                              void* d_out, int out_size, void* d_ws, size_t ws_size,
                              hipStream_t stream)
{
  const float* Q    = (const float*)d_in[0];
  const float* Km   = (const float*)d_in[1];
  const float* V    = (const float*)d_in[2];
  const float* mask = (const float*)d_in[3];
  float* out = (float*)d_out;

  const long qsz = in_sizes[0];          // B*S*E
  const long msz = in_sizes[3];          // B*S*S
  const long E = 1024;
  const long S = (msz / qsz) * E;        // 2048
  const long B = qsz / (S * E);          // 4
  const long G = B * S;
  const float scale = 1.0f / sqrtf((float)E);

  // ---- MERGED single-pass path: Qb|Kb|Sbuf, VTb aliases Qb after QK^T ----
  const size_t mergedBytes = (size_t)(2 * qsz) * 2 + (size_t)G * S * 2;
  const long nwgQK = (S / 256) * (G / 256);
  const long nwgPV = (E / 128) * (G / 256);
  const long NTpv  = S / 64;             // PV K-tiles
  if (ws_size >= mergedBytes && (S % 512) == 0 && (G % 256) == 0 &&
      (E % 128) == 0 && (nwgQK % 8) == 0 && (nwgPV % 8) == 0 &&
      NTpv >= 5 && ((NTpv - 2) % 3) == 0) {
    char* w = (char*)d_ws;
    u16* Qb   = (u16*)w;
    u16* Kb   = (u16*)(w + (size_t)qsz * 2);
    u16* Sbuf = (u16*)(w + (size_t)(2 * qsz) * 2);
    u16* VTb  = Qb;   // alias: written only after QK^T is done with Qb

    cvt2_f32_bf16<<<dim3((unsigned)(2 * qsz / 2048)), 256, 0, stream>>>(
        Q, Qb, Km, Kb, qsz);

    // QK^T: 8-phase 256x256 + T2 swizzle + T1 XCD swizzle (1D grid)
    gemm_bt_256<<<dim3((unsigned)nwgQK), 512, 0, stream>>>(
        Qb, (int)E, Kb, (int)E, S * E,
        Sbuf, (int)S, (int)E, scale, (int)S, (int)(S / 256));

    softmax_rows_wave<<<dim3((unsigned)(G / 4)), 256, 0, stream>>>(
        Sbuf, mask, (int)S);

    transcvt_v<<<dim3(S / 64, E / 64, B), 256, 0, stream>>>(V, VTb, (int)S, (int)E);

    // PV: 1-phase-per-tile 3-ring BM256xBN128 + T1 XCD swizzle, fp32 out
    gemm_pv_256<<<dim3((unsigned)nwgPV), 512, 0, stream>>>(
        Sbuf, (int)S, VTb, (int)S, E * S,
        out, (int)E, (int)S, (int)S, (int)(E / 128));
    return;
  }

  // ---- fallback: chunked path ----
  const size_t convBytes = (size_t)(3 * qsz) * 2;   // Qb + Kb + VTb (bf16)
  const size_t rowBytes  = (size_t)S * 2;           // one bf16 score row
  char* w = (char*)d_ws;
  size_t avail = ws_size;
  const bool haveConv = (ws_size >= convBytes + 128 * rowBytes);

  u16 *Qb = nullptr, *Kb = nullptr, *VTb = nullptr;
  if (haveConv) {
    Qb  = (u16*)w;              w += (size_t)qsz * 2;
    Kb  = (u16*)w;              w += (size_t)qsz * 2;
    VTb = (u16*)w;              w += (size_t)qsz * 2;
    avail -= convBytes;
  }
  long Rmax = (long)((avail / rowBytes) / 128) * 128;
  if (Rmax > G) Rmax = G;
  if (Rmax < 128) Rmax = 128;
  u16* Sbuf = (u16*)w;

  if (haveConv) {
    cvt_f32_bf16<<<dim3((unsigned)(qsz / 2048)), 256, 0, stream>>>(Q, Qb, qsz);
    cvt_f32_bf16<<<dim3((unsigned)(qsz / 2048)), 256, 0, stream>>>(Km, Kb, qsz);
    transcvt_v<<<dim3(S / 64, E / 64, B), 256, 0, stream>>>(V, VTb, (int)S, (int)E);
  }

  for (long g0 = 0; g0 < G; g0 += Rmax) {
    const long R = (G - g0 < Rmax) ? (G - g0) : Rmax;
    if (haveConv) {
      gemm_bt_fast<1, 0><<<dim3(S / 128, R / 128), 256, 0, stream>>>(
          Qb, (int)E, 0L, Kb, (int)E, S * E,
          Sbuf, (int)S, g0, mask, (int)E, scale, g0, (int)S);
    } else {
      gemm_bt<1, 1, 0, 1, 0><<<dim3(S / 128, R / 128), 256, 0, stream>>>(
          Q, (int)E, 0L, Km, (int)E, S * E,
          Sbuf, (int)S, g0, mask, (int)E, scale, g0, (int)S);
    }
    softmax_rows<0><<<dim3(R), 256, 0, stream>>>(Sbuf, nullptr, (int)S);
    if (haveConv) {
      gemm_bt_fast<0, 1><<<dim3(E / 128, R / 128), 256, 0, stream>>>(
          Sbuf, (int)S, g0, VTb, (int)S, E * S,
          out, (int)E, 0L, nullptr, (int)S, 1.0f, g0, (int)S);
    } else {
      gemm_bt<0, 1, 1, 0, 1><<<dim3(E / 128, R / 128), 256, 0, stream>>>(
          Sbuf, (int)S, g0, V, (int)E, S * E,
          out, (int)E, 0L, nullptr, (int)S, 1.0f, g0, (int)S);
    }
  }
}

// Round 15
// 263.001 us; speedup vs baseline: 1.0046x; 1.0046x over previous
//
#include <hip/hip_runtime.h>
#include <stdint.h>
#include <math.h>

typedef unsigned short u16;
typedef short bf16x8 __attribute__((ext_vector_type(8)));
typedef unsigned short u16x8 __attribute__((ext_vector_type(8)));
typedef unsigned short u16x4 __attribute__((ext_vector_type(4)));
typedef float f32x4 __attribute__((ext_vector_type(4)));

typedef __attribute__((address_space(1))) const void gvoid;
typedef __attribute__((address_space(3))) void lvoid;

#define LOG2E 1.4426950408889634f

__device__ __forceinline__ float bf2f(u16 u) {
  union { unsigned int i; float f; } v; v.i = ((unsigned int)u) << 16; return v.f;
}
__device__ __forceinline__ u16 f2bf(float f) {
  union { float ff; unsigned int i; } v; v.ff = f;
  unsigned int x = v.i;
  return (u16)((x + 0x7FFFu + ((x >> 16) & 1u)) >> 16);
}

// T1 bijective chunked XCD swizzle (nwg % 8 == 0): consecutive remapped
// wgid (which share operand panels) land on the SAME XCD's L2.
__device__ __forceinline__ int xcd_swz(int o, int nwg) {
  return (o & 7) * (nwg >> 3) + (o >> 3);
}

// ---------------------------------------------------------------------------
// fp32 -> bf16 flat convert of TWO buffers in one dispatch (Q then K).
// ---------------------------------------------------------------------------
__global__ __launch_bounds__(256)
void cvt2_f32_bf16(const float* __restrict__ s0, u16* __restrict__ d0,
                   const float* __restrict__ s1, u16* __restrict__ d1, long n)
{
  const long nb = n / 2048;
  const float* src = (blockIdx.x < nb) ? s0 : s1;
  u16* dst         = (blockIdx.x < nb) ? d0 : d1;
  const long bid   = (blockIdx.x < nb) ? blockIdx.x : (blockIdx.x - nb);
  long i = (bid * 256 + threadIdx.x) * 8;
  if (i + 8 > n) return;
  f32x4 a = *(const f32x4*)&src[i];
  f32x4 b = *(const f32x4*)&src[i + 4];
  u16x8 o;
#pragma unroll
  for (int j = 0; j < 4; j++) { o[j] = f2bf(a[j]); o[4 + j] = f2bf(b[j]); }
  *(u16x8*)&dst[i] = o;
}

__global__ __launch_bounds__(256)
void cvt_f32_bf16(const float* __restrict__ src, u16* __restrict__ dst, long n)
{
  long i = ((long)blockIdx.x * 256 + threadIdx.x) * 8;
  if (i + 8 > n) return;
  f32x4 a = *(const f32x4*)&src[i];
  f32x4 b = *(const f32x4*)&src[i + 4];
  u16x8 o;
#pragma unroll
  for (int j = 0; j < 4; j++) { o[j] = f2bf(a[j]); o[4 + j] = f2bf(b[j]); }
  *(u16x8*)&dst[i] = o;
}

// ---------------------------------------------------------------------------
// Per-batch transpose+convert: VT[b][n][k] = (bf16)V[b][k][n]. 64x64 tiles.
// ---------------------------------------------------------------------------
__global__ __launch_bounds__(256)
void transcvt_v(const float* __restrict__ V, u16* __restrict__ VT, int S, int E)
{
  __shared__ u16 t[64][72];
  const int b = blockIdx.z;
  const float* Vb = V + (long)b * S * E;
  u16* VTb = VT + (long)b * S * E;
  const int k0 = blockIdx.x * 64, n0 = blockIdx.y * 64;
  const int tid = threadIdx.x;
#pragma unroll
  for (int p = 0; p < 2; p++) {
    int kk = p * 32 + (tid >> 3);
    int nn = (tid & 7) * 8;
    f32x4 a = *(const f32x4*)&Vb[(long)(k0 + kk) * E + n0 + nn];
    f32x4 c = *(const f32x4*)&Vb[(long)(k0 + kk) * E + n0 + nn + 4];
#pragma unroll
    for (int j = 0; j < 4; j++) { t[nn + j][kk] = f2bf(a[j]); t[nn + 4 + j][kk] = f2bf(c[j]); }
  }
  __syncthreads();
#pragma unroll
  for (int p = 0; p < 2; p++) {
    int nn = p * 32 + (tid >> 3);
    int kk = (tid & 7) * 8;
    u16x8 u;
#pragma unroll
    for (int j = 0; j < 8; j++) u[j] = t[nn][kk + j];
    *(u16x8*)&VTb[(long)(n0 + nn) * S + k0 + kk] = u;
  }
}

// ===========================================================================
// 256x256 / 8-phase / counted-vmcnt bf16 GEMM (B^T layout), T3+T4+T5 + T2
// + T1 XCD swizzle (1D grid). (Schedule verified rounds 9/10/13.)
// ===========================================================================
__global__ __launch_bounds__(512, 1)
void gemm_bt_256(const u16* __restrict__ A, int lda,
                 const u16* __restrict__ B, int ldb, long bBatchStride,
                 u16* __restrict__ C, int ldc,
                 int K, float scale, int S, int nbx)
{
  __shared__ u16 LA[2][256][64];
  __shared__ u16 LB[2][256][64];

  const int tid  = threadIdx.x;
  const int lane = tid & 63;
  const int wave = tid >> 6;        // 0..7
  const int wm   = wave >> 2;       // 0..1
  const int wn   = wave & 3;        // 0..3

  const int wgid = xcd_swz(blockIdx.x, gridDim.x);
  const int by   = wgid / nbx;
  const int bx   = wgid - by * nbx;

  const long gTile = (long)by * 256;
  const int  bidx  = (int)(gTile / S);
  const int  nTile = bx * 256;

  const u16* Ab = A + gTile * (long)lda;
  const u16* Bb = B + (long)bidx * bBatchStride + (long)nTile * ldb;

  const int lm  = lane & 15;
  const int lmx = lm & 7;
  const int l47 = lane >> 4;
  const int srw = lane >> 3;
  const int scg = (((lane & 7) ^ (lane >> 3)) * 8);   // T2 pre-swizzled src granule

  f32x4 acc[8][4];
#pragma unroll
  for (int i = 0; i < 8; i++)
#pragma unroll
    for (int j = 0; j < 4; j++) acc[i][j] = (f32x4){0.f, 0.f, 0.f, 0.f};

  bf16x8 afr[8], bA[4], bB[4];

#define STG_A(buf, T, h)                                                      \
  {                                                                           \
    _Pragma("unroll")                                                         \
    for (int p_ = 0; p_ < 2; p_++) {                                          \
      const int ch_ = wave * 2 + p_;                                          \
      const int rr_ = (h) * 128 + ch_ * 8 + srw;                              \
      __builtin_amdgcn_global_load_lds(                                       \
          (gvoid*)&Ab[(long)rr_ * lda + (T) * 64 + scg],                      \
          (lvoid*)((char*)&LA[0][0][0] + (buf) * 32768 + (h) * 16384 + ch_ * 1024), \
          16, 0, 0);                                                          \
    }                                                                         \
  }
#define STG_B(buf, T, h)                                                      \
  {                                                                           \
    _Pragma("unroll")                                                         \
    for (int p_ = 0; p_ < 2; p_++) {                                          \
      const int ch_ = wave * 2 + p_;                                          \
      const int rr_ = (h) * 128 + ch_ * 8 + srw;                              \
      __builtin_amdgcn_global_load_lds(                                       \
          (gvoid*)&Bb[(long)rr_ * ldb + (T) * 64 + scg],                      \
          (lvoid*)((char*)&LB[0][0][0] + (buf) * 32768 + (h) * 16384 + ch_ * 1024), \
          16, 0, 0);                                                          \
    }                                                                         \
  }
#define LDA_HALF(buf, mh)                                                     \
  {                                                                           \
    _Pragma("unroll")                                                         \
    for (int m_ = 0; m_ < 4; m_++)                                            \
      _Pragma("unroll")                                                       \
      for (int kk_ = 0; kk_ < 2; kk_++)                                       \
        afr[m_ * 2 + kk_] = *(const bf16x8*)&LA[buf][wm * 128 + ((mh) * 4 + m_) * 16 + lm][(((kk_ * 4 + l47) ^ lmx) * 8)]; \
  }
#define LDB_HALF(buf, nh, dst)                                                \
  {                                                                           \
    _Pragma("unroll")                                                         \
    for (int n_ = 0; n_ < 2; n_++)                                            \
      _Pragma("unroll")                                                       \
      for (int kk_ = 0; kk_ < 2; kk_++)                                       \
        dst[n_ * 2 + kk_] = *(const bf16x8*)&LB[buf][wn * 64 + ((nh) * 2 + n_) * 16 + lm][(((kk_ * 4 + l47) ^ lmx) * 8)]; \
  }
#define PH(mh, nh, bp)                                                        \
  {                                                                           \
    __builtin_amdgcn_sched_barrier(0);                                        \
    __builtin_amdgcn_s_barrier();                                             \
    asm volatile("s_waitcnt lgkmcnt(0)" ::: "memory");                        \
    __builtin_amdgcn_sched_barrier(0);                                        \
    __builtin_amdgcn_s_setprio(1);                                            \
    _Pragma("unroll")                                                         \
    for (int m_ = 0; m_ < 4; m_++)                                            \
      _Pragma("unroll")                                                       \
      for (int n_ = 0; n_ < 2; n_++)                                          \
        _Pragma("unroll")                                                     \
        for (int kk_ = 0; kk_ < 2; kk_++)                                     \
          acc[(mh) * 4 + m_][(nh) * 2 + n_] =                                 \
              __builtin_amdgcn_mfma_f32_16x16x32_bf16(                        \
                  afr[m_ * 2 + kk_], bp[n_ * 2 + kk_],                        \
                  acc[(mh) * 4 + m_][(nh) * 2 + n_], 0, 0, 0);                \
    __builtin_amdgcn_s_setprio(0);                                            \
    __builtin_amdgcn_sched_barrier(0);                                        \
    __builtin_amdgcn_s_barrier();                                             \
  }

  const int NT = K >> 6;
  const int NI = NT >> 1;

  STG_A(0, 0, 0); STG_A(0, 0, 1); STG_B(0, 0, 0); STG_B(0, 0, 1);
  STG_A(1, 1, 0); STG_B(1, 1, 0);
  asm volatile("s_waitcnt vmcnt(0)" ::: "memory");
  __builtin_amdgcn_sched_barrier(0);
  __builtin_amdgcn_s_barrier();

  for (int i = 0; i < NI - 1; i++) {
    const int t0 = 2 * i, t1 = t0 + 1;
    LDA_HALF(0, 0); LDB_HALF(0, 0, bA);
    STG_B(1, t1, 1);
    PH(0, 0, bA);
    LDB_HALF(0, 1, bB);
    STG_A(1, t1, 1);
    PH(0, 1, bB);
    LDA_HALF(0, 1);
    STG_A(0, t0 + 2, 0);
    PH(1, 0, bA);
    STG_B(0, t0 + 2, 0);
    asm volatile("s_waitcnt vmcnt(4)" ::: "memory");
    PH(1, 1, bB);
    LDA_HALF(1, 0); LDB_HALF(1, 0, bA);
    STG_B(0, t0 + 2, 1);
    PH(0, 0, bA);
    LDB_HALF(1, 1, bB);
    STG_A(0, t0 + 2, 1);
    PH(0, 1, bB);
    LDA_HALF(1, 1);
    STG_A(1, t1 + 2, 0);
    PH(1, 0, bA);
    STG_B(1, t1 + 2, 0);
    asm volatile("s_waitcnt vmcnt(4)" ::: "memory");
    PH(1, 1, bB);
  }

  {
    const int t1 = NT - 1;
    LDA_HALF(0, 0); LDB_HALF(0, 0, bA);
    STG_B(1, t1, 1);
    PH(0, 0, bA);
    LDB_HALF(0, 1, bB);
    STG_A(1, t1, 1);
    PH(0, 1, bB);
    LDA_HALF(0, 1);
    PH(1, 0, bA);
    asm volatile("s_waitcnt vmcnt(0)" ::: "memory");
    PH(1, 1, bB);
    LDA_HALF(1, 0); LDB_HALF(1, 0, bA);
    PH(0, 0, bA);
    LDB_HALF(1, 1, bB);
    PH(0, 1, bB);
    LDA_HALF(1, 1);
    PH(1, 0, bA);
    PH(1, 1, bB);
  }

  const int lr = (lane >> 4) * 4;
#pragma unroll
  for (int mf = 0; mf < 8; mf++) {
#pragma unroll
    for (int nf = 0; nf < 4; nf++) {
      long gr = gTile + wm * 128 + mf * 16 + lr;
      int  cc = nTile + wn * 64 + nf * 16 + lm;
#pragma unroll
      for (int i2 = 0; i2 < 4; i2++)
        C[(gr + i2) * (long)ldc + cc] = f2bf(acc[mf][nf][i2] * scale);
    }
  }
#undef STG_A
#undef STG_B
#undef LDA_HALF
#undef LDB_HALF
#undef PH
}

// ===========================================================================
// PV GEMM, 4-phase / 16-MFMA-per-phase, 2-buffer (verified rounds 12/13)
// + T1 XCD swizzle. BM=256 x BN=128, grid 1D (E/128)*(G/256)=256 blocks.
// 8 waves 4Mx2N, per-wave 64x64, acc[4][4]. Counted waits vmcnt(3) at
// P2/P4 (derivations in R12 post-mortem, verified). fp32 out. 96 KB LDS.
// ===========================================================================
__global__ __launch_bounds__(512, 1)
void gemm_pv_256(const u16* __restrict__ A, int lda,
                 const u16* __restrict__ B, int ldb, long bBatchStride,
                 float* __restrict__ C, int ldc,
                 int K, int S, int nbx)
{
  __shared__ u16 LA[2][256][64];
  __shared__ u16 LB[2][128][64];

  const int tid  = threadIdx.x;
  const int lane = tid & 63;
  const int wave = tid >> 6;        // 0..7
  const int wm   = wave >> 1;       // 0..3  (M quarter, 64 rows)
  const int wn   = wave & 1;        // 0..1  (N half, 64 cols)

  const int wgid = xcd_swz(blockIdx.x, gridDim.x);
  const int by   = wgid / nbx;
  const int bx   = wgid - by * nbx;

  const long gTile = (long)by * 256;
  const int  bidx  = (int)(gTile / S);
  const int  nTile = bx * 128;

  const u16* Ab = A + gTile * (long)lda;
  const u16* Bb = B + (long)bidx * bBatchStride + (long)nTile * ldb;

  const int lm  = lane & 15;
  const int lmx = lm & 7;
  const int l47 = lane >> 4;
  const int srw = lane >> 3;
  const int scg = (((lane & 7) ^ (lane >> 3)) * 8);   // T2 pre-swizzled src granule

  f32x4 acc[4][4];
#pragma unroll
  for (int i = 0; i < 4; i++)
#pragma unroll
    for (int j = 0; j < 4; j++) acc[i][j] = (f32x4){0.f, 0.f, 0.f, 0.f};

  bf16x8 afr[4], ball[8];

#define STG_A(buf, T, h)                                                      \
  {                                                                           \
    _Pragma("unroll")                                                         \
    for (int p_ = 0; p_ < 2; p_++) {                                          \
      const int ch_ = wave * 2 + p_;                                          \
      const int rr_ = (h) * 128 + ch_ * 8 + srw;                              \
      __builtin_amdgcn_global_load_lds(                                       \
          (gvoid*)&Ab[(long)rr_ * lda + (T) * 64 + scg],                      \
          (lvoid*)((char*)&LA[0][0][0] + (buf) * 32768 + (h) * 16384 + ch_ * 1024), \
          16, 0, 0);                                                          \
    }                                                                         \
  }
#define STG_B(buf, T, h)                                                      \
  {                                                                           \
    const int rr_ = (h) * 64 + wave * 8 + srw;                                \
    __builtin_amdgcn_global_load_lds(                                         \
        (gvoid*)&Bb[(long)rr_ * ldb + (T) * 64 + scg],                        \
        (lvoid*)((char*)&LB[0][0][0] + (buf) * 16384 + (h) * 8192 + wave * 1024), \
        16, 0, 0);                                                            \
  }
#define LDA_HALF(buf, mh)                                                     \
  {                                                                           \
    _Pragma("unroll")                                                         \
    for (int m_ = 0; m_ < 2; m_++)                                            \
      _Pragma("unroll")                                                       \
      for (int kk_ = 0; kk_ < 2; kk_++)                                       \
        afr[m_ * 2 + kk_] = *(const bf16x8*)&LA[buf][wm * 64 + ((mh) * 2 + m_) * 16 + lm][(((kk_ * 4 + l47) ^ lmx) * 8)]; \
  }
#define LDB_ALL(buf)                                                          \
  {                                                                           \
    _Pragma("unroll")                                                         \
    for (int n_ = 0; n_ < 4; n_++)                                            \
      _Pragma("unroll")                                                       \
      for (int kk_ = 0; kk_ < 2; kk_++)                                       \
        ball[n_ * 2 + kk_] = *(const bf16x8*)&LB[buf][wn * 64 + n_ * 16 + lm][(((kk_ * 4 + l47) ^ lmx) * 8)]; \
  }
#define PH(mh)                                                                \
  {                                                                           \
    __builtin_amdgcn_sched_barrier(0);                                        \
    __builtin_amdgcn_s_barrier();                                             \
    asm volatile("s_waitcnt lgkmcnt(0)" ::: "memory");                        \
    __builtin_amdgcn_sched_barrier(0);                                        \
    __builtin_amdgcn_s_setprio(1);                                            \
    _Pragma("unroll")                                                         \
    for (int m_ = 0; m_ < 2; m_++)                                            \
      _Pragma("unroll")                                                       \
      for (int n_ = 0; n_ < 4; n_++)                                          \
        _Pragma("unroll")                                                     \
        for (int kk_ = 0; kk_ < 2; kk_++)                                     \
          acc[(mh) * 2 + m_][n_] =                                            \
              __builtin_amdgcn_mfma_f32_16x16x32_bf16(                        \
                  afr[m_ * 2 + kk_], ball[n_ * 2 + kk_],                      \
                  acc[(mh) * 2 + m_][n_], 0, 0, 0);                           \
    __builtin_amdgcn_s_setprio(0);                                            \
    __builtin_amdgcn_sched_barrier(0);                                        \
    __builtin_amdgcn_s_barrier();                                             \
  }

  const int NT = K >> 6;
  const int NI = NT >> 1;

  // prologue: t0 full (A 4 + B 2 = 6 loads), t1 lo (A 2 + B 1 = 3 loads)
  STG_A(0, 0, 0); STG_A(0, 0, 1); STG_B(0, 0, 0); STG_B(0, 0, 1);
  STG_A(1, 1, 0); STG_B(1, 1, 0);
  asm volatile("s_waitcnt vmcnt(0)" ::: "memory");
  __builtin_amdgcn_sched_barrier(0);
  __builtin_amdgcn_s_barrier();

  for (int i = 0; i < NI - 1; i++) {
    const int t0 = 2 * i, t1 = t0 + 1;
    // P1: reads b0 (t0): A-lo frags + all B; stage t1's hi halves (3)
    LDA_HALF(0, 0); LDB_ALL(0);
    STG_B(1, t1, 1);
    STG_A(1, t1, 1);
    PH(0);
    // P2: reads b0 A-hi; stage t0+2 lo (3); drain t1 (6 old) -> vmcnt(3)
    LDA_HALF(0, 1);
    STG_A(0, t0 + 2, 0);
    STG_B(0, t0 + 2, 0);
    asm volatile("s_waitcnt vmcnt(3)" ::: "memory");
    PH(1);
    // P3: reads b1 (t1): A-lo + all B; stage t0+2 hi (3)
    LDA_HALF(1, 0); LDB_ALL(1);
    STG_B(0, t0 + 2, 1);
    STG_A(0, t0 + 2, 1);
    PH(0);
    // P4: reads b1 A-hi; stage t1+2 lo (3); drain t0+2 (6 old) -> vmcnt(3)
    LDA_HALF(1, 1);
    STG_A(1, t1 + 2, 0);
    STG_B(1, t1 + 2, 0);
    asm volatile("s_waitcnt vmcnt(3)" ::: "memory");
    PH(1);
  }

  // tail iteration (tiles NT-2, NT-1): stage only t1's hi at P1
  {
    const int t1 = NT - 1;
    LDA_HALF(0, 0); LDB_ALL(0);
    STG_B(1, t1, 1);
    STG_A(1, t1, 1);
    PH(0);
    LDA_HALF(0, 1);
    asm volatile("s_waitcnt vmcnt(0)" ::: "memory");
    PH(1);
    LDA_HALF(1, 0); LDB_ALL(1);
    PH(0);
    LDA_HALF(1, 1);
    PH(1);
  }

  // epilogue: fp32 out; C/D layout col = lane&15, row = (lane>>4)*4 + reg
  const int lr = (lane >> 4) * 4;
#pragma unroll
  for (int mf = 0; mf < 4; mf++) {
#pragma unroll
    for (int nf = 0; nf < 4; nf++) {
      long gr = gTile + wm * 64 + mf * 16 + lr;
      int  cc = nTile + wn * 64 + nf * 16 + lm;
#pragma unroll
      for (int i2 = 0; i2 < 4; i2++)
        C[(gr + i2) * (long)ldc + cc] = acc[mf][nf][i2];
    }
  }
#undef STG_A
#undef STG_B
#undef LDA_HALF
#undef LDB_ALL
#undef PH
}

// ---------------------------------------------------------------------------
// FAST bf16 GEMM (BT layout), m97 structure (fallback chunked path).
// ---------------------------------------------------------------------------
template<int HASMASK, int COUT>
__global__ __launch_bounds__(256, 3)
void gemm_bt_fast(const u16* __restrict__ A, int lda, long aRowOff,
                  const u16* __restrict__ B, int ldb, long bBatchStride,
                  void* __restrict__ Cp, int ldc, long cRowOff,
                  const float* __restrict__ maskf,
                  int K, float scale, long g0, int S)
{
  const int tid  = threadIdx.x;
  const int lane = tid & 63;
  const int wave = tid >> 6;
  const long gTile = g0 + (long)blockIdx.y * 128;
  const int  bidx  = (int)(gTile / S);
  const int  nTile = blockIdx.x * 128;

  __shared__ u16 As[128][32];
  __shared__ u16 Bs[128][32];

  const u16* Ab = A + (gTile - aRowOff) * (long)lda;
  const u16* Bb = B + (long)bidx * bBatchStride + (long)nTile * ldb;

  const int qm = (wave >> 1) * 64;
  const int qn = (wave & 1) * 64;
  const int lm  = lane & 15;
  const int lkB = (lane >> 4) * 16;

  const int sr = lane >> 2;
  const int sc = (lane & 3) * 8;

  f32x4 acc[4][4];
#pragma unroll
  for (int i = 0; i < 4; i++)
#pragma unroll
    for (int j = 0; j < 4; j++) acc[i][j] = (f32x4){0.f, 0.f, 0.f, 0.f};

  for (int k0 = 0; k0 < K; k0 += 32) {
#pragma unroll
    for (int p = 0; p < 2; p++) {
      const int chunk = wave * 2 + p;
      const int r = chunk * 16 + sr;
      __builtin_amdgcn_global_load_lds(
          (gvoid*)&Ab[(long)r * lda + k0 + sc],
          (lvoid*)((char*)&As[0][0] + chunk * 1024),
          16, 0, 0);
      __builtin_amdgcn_global_load_lds(
          (gvoid*)&Bb[(long)r * ldb + k0 + sc],
          (lvoid*)((char*)&Bs[0][0] + chunk * 1024),
          16, 0, 0);
    }
    __syncthreads();

    bf16x8 af[4], bfr[4];
#pragma unroll
    for (int rt = 0; rt < 4; rt++)
      af[rt] = *(const bf16x8*)((const char*)&As[qm + rt * 16 + lm][0] + lkB);
#pragma unroll
    for (int ct = 0; ct < 4; ct++)
      bfr[ct] = *(const bf16x8*)((const char*)&Bs[qn + ct * 16 + lm][0] + lkB);

#pragma unroll
    for (int rt = 0; rt < 4; rt++)
#pragma unroll
      for (int ct = 0; ct < 4; ct++)
        acc[rt][ct] = __builtin_amdgcn_mfma_f32_16x16x32_bf16(af[rt], bfr[ct], acc[rt][ct], 0, 0, 0);
    __syncthreads();
  }

  const int lr = (lane >> 4) * 4;
#pragma unroll
  for (int rt = 0; rt < 4; rt++) {
#pragma unroll
    for (int ct = 0; ct < 4; ct++) {
      long gr = gTile + qm + rt * 16 + lr;
      int  cc = nTile + qn + ct * 16 + lm;
#pragma unroll
      for (int i = 0; i < 4; i++) {
        float v = acc[rt][ct][i] * scale;
        if (HASMASK) v += maskf[(gr + i) * (long)ldc + cc];
        if (COUT == 0)
          ((u16*)Cp)[(gr + i - cRowOff) * (long)ldc + cc] = f2bf(v);
        else
          ((float*)Cp)[(gr + i - cRowOff) * (long)ldc + cc] = v;
      }
    }
  }
}

// ---------------------------------------------------------------------------
// GEMM (BT layout) — generic fallback (fp32 sources, no-workspace path).
// ---------------------------------------------------------------------------
template<int ASRC, int BSRC, int BMODE, int HASMASK, int COUT>
__global__ __launch_bounds__(256, 2)
void gemm_bt(const void* __restrict__ Ap, int lda, long aRowOff,
             const void* __restrict__ Bp, int ldb, long bBatchStride,
             void* __restrict__ Cp, int ldc, long cRowOff,
             const float* __restrict__ maskf,
             int K, float scale, long g0, int S)
{
  const int tid  = threadIdx.x;
  const int lane = tid & 63;
  const int wave = tid >> 6;
  const long gTile = g0 + (long)blockIdx.y * 128;
  const int  b     = (int)(gTile / S);
  const int  nTile = blockIdx.x * 128;

  __shared__ u16 As[128][40];
  __shared__ u16 Bs[128][40];

  const int qm = (wave >> 1) * 64;
  const int qn = (wave & 1) * 64;

  f32x4 acc[4][4];
#pragma unroll
  for (int i = 0; i < 4; i++)
#pragma unroll
    for (int j = 0; j < 4; j++) acc[i][j] = (f32x4){0.f, 0.f, 0.f, 0.f};

  const u16*   Ab = (const u16*)Ap   + (gTile - aRowOff) * (long)lda;
  const float* Af = (const float*)Ap + (gTile - aRowOff) * (long)lda;
  const u16*   Bb = (const u16*)Bp   + (long)b * bBatchStride;
  const float* Bf = (const float*)Bp + (long)b * bBatchStride;

  const int lm = lane & 15;
  const int lk = (lane >> 4) * 8;

  for (int k0 = 0; k0 < K; k0 += 32) {
    if (ASRC == 0) {
      int srow = tid >> 2, scol = (tid & 3) * 8;
#pragma unroll
      for (int p = 0; p < 2; p++) {
        int r = p * 64 + srow;
        *(u16x8*)&As[r][scol] = *(const u16x8*)&Ab[(long)r * lda + k0 + scol];
      }
    } else {
      int srow = tid >> 3, scol = (tid & 7) * 4;
#pragma unroll
      for (int p = 0; p < 4; p++) {
        int r = p * 32 + srow;
        f32x4 a = *(const f32x4*)&Af[(long)r * lda + k0 + scol];
        u16x4 o;
#pragma unroll
        for (int j = 0; j < 4; j++) o[j] = f2bf(a[j]);
        *(u16x4*)&As[r][scol] = o;
      }
    }
    if (BMODE == 0) {
      if (BSRC == 0) {
        int srow = tid >> 2, scol = (tid & 3) * 8;
#pragma unroll
        for (int p = 0; p < 2; p++) {
          int r = p * 64 + srow;
          *(u16x8*)&Bs[r][scol] = *(const u16x8*)&Bb[(long)(nTile + r) * ldb + k0 + scol];
        }
      } else {
        int srow = tid >> 3, scol = (tid & 7) * 4;
#pragma unroll
        for (int p = 0; p < 4; p++) {
          int r = p * 32 + srow;
          f32x4 a = *(const f32x4*)&Bf[(long)(nTile + r) * ldb + k0 + scol];
          u16x4 o;
#pragma unroll
          for (int j = 0; j < 4; j++) o[j] = f2bf(a[j]);
          *(u16x4*)&Bs[r][scol] = o;
        }
      }
    }
    __syncthreads();

    bf16x8 af[4], bfr[4];
#pragma unroll
    for (int rt = 0; rt < 4; rt++)
      af[rt] = *(const bf16x8*)&As[qm + rt * 16 + lm][lk];
    if (BMODE == 0) {
#pragma unroll
      for (int ct = 0; ct < 4; ct++)
        bfr[ct] = *(const bf16x8*)&Bs[qn + ct * 16 + lm][lk];
    } else {
#pragma unroll
      for (int ct = 0; ct < 4; ct++) {
        const float* vp = Bf + (long)(k0 + lk) * ldb + nTile + qn + ct * 16 + lm;
#pragma unroll
        for (int j = 0; j < 8; j++) bfr[ct][j] = (short)f2bf(vp[(long)j * ldb]);
      }
    }
#pragma unroll
    for (int rt = 0; rt < 4; rt++)
#pragma unroll
      for (int ct = 0; ct < 4; ct++)
        acc[rt][ct] = __builtin_amdgcn_mfma_f32_16x16x32_bf16(af[rt], bfr[ct], acc[rt][ct], 0, 0, 0);
    __syncthreads();
  }

  const int lr = (lane >> 4) * 4;
#pragma unroll
  for (int rt = 0; rt < 4; rt++) {
#pragma unroll
    for (int ct = 0; ct < 4; ct++) {
      long gr = gTile + qm + rt * 16 + lr;
      int  cc = nTile + qn + ct * 16 + lm;
#pragma unroll
      for (int i = 0; i < 4; i++) {
        float v = acc[rt][ct][i] * scale;
        if (HASMASK) v += maskf[(gr + i) * (long)ldc + cc];
        if (COUT == 0)
          ((u16*)Cp)[(gr + i - cRowOff) * (long)ldc + cc] = f2bf(v);
        else
          ((float*)Cp)[(gr + i - cRowOff) * (long)ldc + cc] = v;
      }
    }
  }
}

// ---------------------------------------------------------------------------
// Wave-per-row softmax (+fp32 mask add), 4 rows per 256-thr block.
// ---------------------------------------------------------------------------
__global__ __launch_bounds__(256)
void softmax_rows_wave(u16* __restrict__ Sbuf, const float* __restrict__ maskf,
                       int ncols)
{
  const int wave = threadIdx.x >> 6;
  const int lane = threadIdx.x & 63;
  const long row = (long)blockIdx.x * 4 + wave;
  u16* rp = Sbuf + row * (long)ncols;
  const float* mp = maskf + row * (long)ncols;

  float x[32];
  float m = -3.0e38f;
#pragma unroll
  for (int j = 0; j < 4; j++) {
    const int c = j * 512 + lane * 8;
    u16x8 u = *(const u16x8*)&rp[c];
    f32x4 ma = *(const f32x4*)&mp[c];
    f32x4 mb = *(const f32x4*)&mp[c + 4];
#pragma unroll
    for (int i = 0; i < 4; i++) {
      x[j * 8 + i]     = bf2f(u[i])     + ma[i];
      x[j * 8 + 4 + i] = bf2f(u[4 + i]) + mb[i];
    }
#pragma unroll
    for (int i = 0; i < 8; i++) m = fmaxf(m, x[j * 8 + i]);
  }
#pragma unroll
  for (int off = 32; off; off >>= 1) m = fmaxf(m, __shfl_xor(m, off, 64));

  float s = 0.f;
#pragma unroll
  for (int i = 0; i < 32; i++) { x[i] = exp2f((x[i] - m) * LOG2E); s += x[i]; }
#pragma unroll
  for (int off = 32; off; off >>= 1) s += __shfl_xor(s, off, 64);
  const float inv = 1.0f / s;

#pragma unroll
  for (int j = 0; j < 4; j++) {
    const int c = j * 512 + lane * 8;
    u16x8 o;
#pragma unroll
    for (int i = 0; i < 8; i++) o[i] = f2bf(x[j * 8 + i] * inv);
    *(u16x8*)&rp[c] = o;
  }
}

// ---------------------------------------------------------------------------
// Row softmax in place (fallback path), bf16 rows of length ncols == 2048.
// ---------------------------------------------------------------------------
template<int HASM>
__global__ __launch_bounds__(256)
void softmax_rows(u16* __restrict__ Sbuf, const float* __restrict__ maskf, int ncols)
{
  const long row = blockIdx.x;
  u16* rp = Sbuf + row * (long)ncols;
  const int tid = threadIdx.x;

  u16x8 u = *(const u16x8*)&rp[tid * 8];
  float x[8];
  if (HASM) {
    const float* mp = maskf + row * (long)ncols + tid * 8;
    f32x4 ma = *(const f32x4*)&mp[0];
    f32x4 mb = *(const f32x4*)&mp[4];
#pragma unroll
    for (int i = 0; i < 4; i++) { x[i] = bf2f(u[i]) + ma[i]; x[4 + i] = bf2f(u[4 + i]) + mb[i]; }
  } else {
#pragma unroll
    for (int i = 0; i < 8; i++) x[i] = bf2f(u[i]);
  }
  float m = -3.0e38f;
#pragma unroll
  for (int i = 0; i < 8; i++) m = fmaxf(m, x[i]);
#pragma unroll
  for (int off = 32; off; off >>= 1) m = fmaxf(m, __shfl_xor(m, off, 64));
  __shared__ float redm[4];
  if ((tid & 63) == 0) redm[tid >> 6] = m;
  __syncthreads();
  m = fmaxf(fmaxf(redm[0], redm[1]), fmaxf(redm[2], redm[3]));

  float e[8];
  float s = 0.f;
#pragma unroll
  for (int i = 0; i < 8; i++) { e[i] = exp2f((x[i] - m) * LOG2E); s += e[i]; }
#pragma unroll
  for (int off = 32; off; off >>= 1) s += __shfl_xor(s, off, 64);
  __shared__ float reds[4];
  if ((tid & 63) == 0) reds[tid >> 6] = s;
  __syncthreads();
  s = reds[0] + reds[1] + reds[2] + reds[3];

  float inv = 1.0f / s;
  u16x8 o;
#pragma unroll
  for (int i = 0; i < 8; i++) o[i] = f2bf(e[i] * inv);
  *(u16x8*)&rp[tid * 8] = o;
}

extern "C" void kernel_launch(void* const* d_in, const int* in_sizes, int n_in,
                              void* d_out, int out_size, void* d_ws, size_t ws_size,
                              hipStream_t stream)
{
  const float* Q    = (const float*)d_in[0];
  const float* Km   = (const float*)d_in[1];
  const float* V    = (const float*)d_in[2];
  const float* mask = (const float*)d_in[3];
  float* out = (float*)d_out;

  const long qsz = in_sizes[0];          // B*S*E
  const long msz = in_sizes[3];          // B*S*S
  const long E = 1024;
  const long S = (msz / qsz) * E;        // 2048
  const long B = qsz / (S * E);          // 4
  const long G = B * S;
  const float scale = 1.0f / sqrtf((float)E);

  // ---- MERGED single-pass path: Qb|Kb|Sbuf, VTb aliases Qb after QK^T ----
  const size_t mergedBytes = (size_t)(2 * qsz) * 2 + (size_t)G * S * 2;
  const long nwgQK = (S / 256) * (G / 256);
  const long nwgPV = (E / 128) * (G / 256);
  if (ws_size >= mergedBytes && (S % 512) == 0 && (G % 256) == 0 &&
      (E % 128) == 0 && (nwgQK % 8) == 0 && (nwgPV % 8) == 0) {
    char* w = (char*)d_ws;
    u16* Qb   = (u16*)w;
    u16* Kb   = (u16*)(w + (size_t)qsz * 2);
    u16* Sbuf = (u16*)(w + (size_t)(2 * qsz) * 2);
    u16* VTb  = Qb;   // alias: written only after QK^T is done with Qb

    cvt2_f32_bf16<<<dim3((unsigned)(2 * qsz / 2048)), 256, 0, stream>>>(
        Q, Qb, Km, Kb, qsz);

    // QK^T: 8-phase 256x256 + T2 swizzle + T1 XCD swizzle (1D grid)
    gemm_bt_256<<<dim3((unsigned)nwgQK), 512, 0, stream>>>(
        Qb, (int)E, Kb, (int)E, S * E,
        Sbuf, (int)S, (int)E, scale, (int)S, (int)(S / 256));

    softmax_rows_wave<<<dim3((unsigned)(G / 4)), 256, 0, stream>>>(
        Sbuf, mask, (int)S);

    transcvt_v<<<dim3(S / 64, E / 64, B), 256, 0, stream>>>(V, VTb, (int)S, (int)E);

    // PV: 4-phase/16-MFMA BM256xBN128 + T1 XCD swizzle (1D grid), fp32 out
    gemm_pv_256<<<dim3((unsigned)nwgPV), 512, 0, stream>>>(
        Sbuf, (int)S, VTb, (int)S, E * S,
        out, (int)E, (int)S, (int)S, (int)(E / 128));
    return;
  }

  // ---- fallback: chunked path ----
  const size_t convBytes = (size_t)(3 * qsz) * 2;   // Qb + Kb + VTb (bf16)
  const size_t rowBytes  = (size_t)S * 2;           // one bf16 score row
  char* w = (char*)d_ws;
  size_t avail = ws_size;
  const bool haveConv = (ws_size >= convBytes + 128 * rowBytes);

  u16 *Qb = nullptr, *Kb = nullptr, *VTb = nullptr;
  if (haveConv) {
    Qb  = (u16*)w;              w += (size_t)qsz * 2;
    Kb  = (u16*)w;              w += (size_t)qsz * 2;
    VTb = (u16*)w;              w += (size_t)qsz * 2;
    avail -= convBytes;
  }
  long Rmax = (long)((avail / rowBytes) / 128) * 128;
  if (Rmax > G) Rmax = G;
  if (Rmax < 128) Rmax = 128;
  u16* Sbuf = (u16*)w;

  if (haveConv) {
    cvt_f32_bf16<<<dim3((unsigned)(qsz / 2048)), 256, 0, stream>>>(Q, Qb, qsz);
    cvt_f32_bf16<<<dim3((unsigned)(qsz / 2048)), 256, 0, stream>>>(Km, Kb, qsz);
    transcvt_v<<<dim3(S / 64, E / 64, B), 256, 0, stream>>>(V, VTb, (int)S, (int)E);
  }

  for (long g0 = 0; g0 < G; g0 += Rmax) {
    const long R = (G - g0 < Rmax) ? (G - g0) : Rmax;
    if (haveConv) {
      gemm_bt_fast<1, 0><<<dim3(S / 128, R / 128), 256, 0, stream>>>(
          Qb, (int)E, 0L, Kb, (int)E, S * E,
          Sbuf, (int)S, g0, mask, (int)E, scale, g0, (int)S);
    } else {
      gemm_bt<1, 1, 0, 1, 0><<<dim3(S / 128, R / 128), 256, 0, stream>>>(
          Q, (int)E, 0L, Km, (int)E, S * E,
          Sbuf, (int)S, g0, mask, (int)E, scale, g0, (int)S);
    }
    softmax_rows<0><<<dim3(R), 256, 0, stream>>>(Sbuf, nullptr, (int)S);
    if (haveConv) {
      gemm_bt_fast<0, 1><<<dim3(E / 128, R / 128), 256, 0, stream>>>(
          Sbuf, (int)S, g0, VTb, (int)S, E * S,
          out, (int)E, 0L, nullptr, (int)S, 1.0f, g0, (int)S);
    } else {
      gemm_bt<0, 1, 1, 0, 1><<<dim3(E / 128, R / 128), 256, 0, stream>>>(
          Sbuf, (int)S, g0, V, (int)E, S * E,
          out, (int)E, 0L, nullptr, (int)S, 1.0f, g0, (int)S);
    }
  }
}